// Round 1
// baseline (503.877 us; speedup 1.0000x reference)
//
#include <hip/hip_runtime.h>
#include <math.h>

#define B_   16
#define L_   4096
#define H_   512
#define P_   128
#define M_   (B_*L_)    // 65536
#define N1_  (2*P_)     // 256

#define BM 64
#define BN 64
#define BK 16
#define TM 4
#define TN 4

// ---------------- precompute kernels ----------------

__global__ void precompA(const float* __restrict__ lr, const float* __restrict__ li,
                         const float* __restrict__ lstep,
                         float* __restrict__ abar_r, float* __restrict__ abar_i,
                         float* __restrict__ coef_r, float* __restrict__ coef_i) {
    int p = threadIdx.x;
    if (p >= P_) return;
    double lrd = (double)lr[p], lid = (double)li[p];
    double step = exp((double)lstep[p]);       // STEP_RESCALE = 1
    double ar = lrd * step, ai = lid * step;
    double ea = exp(ar);
    double abr = ea * cos(ai), abi = ea * sin(ai);
    abar_r[p] = (float)abr; abar_i[p] = (float)abi;
    // coef = (lambda_bar - 1) / lambda
    double nr = abr - 1.0, ni = abi;
    double den = lrd*lrd + lid*lid;
    coef_r[p] = (float)((nr*lrd + ni*lid) / den);
    coef_i[p] = (float)((ni*lrd - nr*lid) / den);
}

// BT[h][n] : n<128 -> Re(b_bar[n][h]), n>=128 -> Im(b_bar[n-128][h])
__global__ void precompBT(const float* __restrict__ Bin,
                          const float* __restrict__ coef_r, const float* __restrict__ coef_i,
                          float* __restrict__ BT) {
    int idx = blockIdx.x * 256 + threadIdx.x;   // over P_*H_
    if (idx >= P_*H_) return;
    int p = idx / H_, h = idx % H_;
    float br = Bin[(p*H_ + h)*2 + 0], bi = Bin[(p*H_ + h)*2 + 1];
    float cr = coef_r[p], ci = coef_i[p];
    BT[h*N1_ + p]      = cr*br - ci*bi;
    BT[h*N1_ + P_ + p] = cr*bi + ci*br;
}

// CM[k][n] : k<128 -> 2*C_r[n][k], k>=128 -> -2*C_i[n][k-128]
__global__ void precompCM(const float* __restrict__ Cin, float* __restrict__ CM) {
    int idx = blockIdx.x * 256 + threadIdx.x;   // over N1_*H_
    if (idx >= N1_*H_) return;
    int k = idx / H_, n = idx % H_;
    float v;
    if (k < P_) v =  2.0f * Cin[(n*P_ + k)*2 + 0];
    else        v = -2.0f * Cin[(n*P_ + (k-P_))*2 + 1];
    CM[k*H_ + n] = v;
}

// ---------------- GEMM 1: bu = inputs @ BT ----------------
// A: (M_ x 512) row-major (inputs). B: (512 x 256) row-major.
// Output scattered into bu_r/bu_i with layout [b][p][l] (coalesced via LDS transpose).

__global__ __launch_bounds__(256) void gemm1(const float* __restrict__ A,
                                             const float* __restrict__ BT,
                                             float* __restrict__ bu_r,
                                             float* __restrict__ bu_i) {
    __shared__ float As[BK][BM+4];
    __shared__ float Bs[BK][BN+4];
    __shared__ float T[BN][BM+1];
    int tid = threadIdx.x;
    int m0 = blockIdx.y * BM;
    int n0 = blockIdx.x * BN;
    float acc[TM][TN] = {};
    int tm0 = (tid / 16) * TM;
    int tn0 = (tid % 16) * TN;
    int lar = tid / 4;            // A row 0..63
    int lac = (tid % 4) * 4;      // A col 0..12
    int lbr = tid / 16;           // B row 0..15
    int lbc = (tid % 16) * 4;     // B col 0..60
    const int K = H_;
    for (int k0 = 0; k0 < K; k0 += BK) {
        float4 av = *(const float4*)&A[(size_t)(m0 + lar) * K + k0 + lac];
        float4 bv = *(const float4*)&BT[(size_t)(k0 + lbr) * N1_ + n0 + lbc];
        __syncthreads();
        As[lac+0][lar] = av.x; As[lac+1][lar] = av.y;
        As[lac+2][lar] = av.z; As[lac+3][lar] = av.w;
        *(float4*)&Bs[lbr][lbc] = bv;
        __syncthreads();
#pragma unroll
        for (int kk = 0; kk < BK; ++kk) {
            float a[TM], b[TN];
#pragma unroll
            for (int i = 0; i < TM; i++) a[i] = As[kk][tm0+i];
#pragma unroll
            for (int j = 0; j < TN; j++) b[j] = Bs[kk][tn0+j];
#pragma unroll
            for (int i = 0; i < TM; i++)
#pragma unroll
                for (int j = 0; j < TN; j++)
                    acc[i][j] += a[i] * b[j];
        }
    }
    __syncthreads();
#pragma unroll
    for (int i = 0; i < TM; i++)
#pragma unroll
        for (int j = 0; j < TN; j++)
            T[tn0+j][tm0+i] = acc[i][j];
    __syncthreads();
    int b  = m0 >> 12;     // BM divides L_, all rows in one batch
    int l0 = m0 & (L_-1);
#pragma unroll
    for (int j = 0; j < 4; j++) {
        int f   = j * 256 + tid;
        int row = f >> 4;            // 0..63  (n offset within tile)
        int c4  = (f & 15) * 4;      // 0..60  (m offset within tile)
        float4 v = make_float4(T[row][c4], T[row][c4+1], T[row][c4+2], T[row][c4+3]);
        int n = n0 + row;
        float* dst = (n < P_) ? bu_r : bu_i;
        int p = (n < P_) ? n : n - P_;
        *(float4*)&dst[((size_t)(b*P_ + p)) * L_ + l0 + c4] = v;
    }
}

// ---------------- scan: x_l = a * x_{l-1} + bu_l, in place over bu ----------------
// one block per (b,p) series; L_=4096, 256 threads x 16 elements.

__global__ __launch_bounds__(256) void scan_kernel(float* __restrict__ bu_r, float* __restrict__ bu_i,
                                                   const float* __restrict__ abar_r,
                                                   const float* __restrict__ abar_i) {
    __shared__ float sr[16*260];
    __shared__ float si[16*260];
    __shared__ float cr[256], ci[256];
    int t  = threadIdx.x;
    int bp = blockIdx.x;                 // b*128 + p
    int p  = bp & (P_-1);
    size_t base = (size_t)bp * L_;
    float ar = abar_r[p], ai = abar_i[p];
    // coalesced load -> swizzled LDS: addr(l) = (l&15)*260 + (l>>4)
    for (int j = 0; j < 16; j++) {
        int idx = j * 256 + t;
        int g = (idx & 15) * 260 + (idx >> 4);
        sr[g] = bu_r[base + idx];
        si[g] = bu_i[base + idx];
    }
    __syncthreads();
    // local scan of l = 16t..16t+15 (element i at LDS addr i*260+t)
    float xr = 0.f, xi = 0.f;
#pragma unroll
    for (int i = 0; i < 16; i++) {
        int g = i * 260 + t;
        float br = sr[g], bi = si[g];
        float nxr = ar*xr - ai*xi + br;
        float nxi = ar*xi + ai*xr + bi;
        xr = nxr; xi = nxi;
        sr[g] = xr; si[g] = xi;
    }
    // a^16
    float mr = ar, mi = ai;
#pragma unroll
    for (int s = 0; s < 4; s++) { float tr = mr*mr - mi*mi; mi = 2.f*mr*mi; mr = tr; }
    // Hillis-Steele inclusive scan of carries with constant ratio a^16
    cr[t] = xr; ci[t] = xi;
    __syncthreads();
    for (int off = 1; off < 256; off <<= 1) {
        float pr = 0.f, pi = 0.f;
        if (t >= off) { pr = cr[t-off]; pi = ci[t-off]; }
        __syncthreads();
        if (t >= off) {
            float nr2 = mr*pr - mi*pi + cr[t];
            float ni2 = mr*pi + mi*pr + ci[t];
            cr[t] = nr2; ci[t] = ni2;
        }
        __syncthreads();
        float t2 = mr*mr - mi*mi; mi = 2.f*mr*mi; mr = t2;
    }
    // exclusive prefix = inclusive[t-1]; fix-up: x_{16t+i} = local_i + a^{i+1} * x0
    float x0r = 0.f, x0i = 0.f;
    if (t > 0) { x0r = cr[t-1]; x0i = ci[t-1]; }
    float pr_ = ar*x0r - ai*x0i;
    float pi_ = ar*x0i + ai*x0r;
#pragma unroll
    for (int i = 0; i < 16; i++) {
        int g = i * 260 + t;
        sr[g] += pr_; si[g] += pi_;
        float nr2 = ar*pr_ - ai*pi_;
        float ni2 = ar*pi_ + ai*pr_;
        pr_ = nr2; pi_ = ni2;
    }
    __syncthreads();
    // coalesced write back
    for (int j = 0; j < 16; j++) {
        int idx = j * 256 + t;
        int g = (idx & 15) * 260 + (idx >> 4);
        bu_r[base + idx] = sr[g];
        bu_i[base + idx] = si[g];
    }
}

// ---------------- GEMM 2: out = states @ CM + D*inputs ----------------
// A'[m][k] = states (k<128: real part, else imag), read coalesced along l.
// B = CM (256 x 512). Epilogue fused.

__global__ __launch_bounds__(256) void gemm2(const float* __restrict__ S_r,
                                             const float* __restrict__ S_i,
                                             const float* __restrict__ CM,
                                             const float* __restrict__ inputs,
                                             const float* __restrict__ Dv,
                                             float* __restrict__ out) {
    __shared__ float As[BK][BM+4];
    __shared__ float Bs[BK][BN+4];
    int tid = threadIdx.x;
    int m0 = blockIdx.y * BM;
    int n0 = blockIdx.x * BN;
    int b  = m0 >> 12;
    int l0 = m0 & (L_-1);
    float acc[TM][TN] = {};
    int tm0 = (tid / 16) * TM;
    int tn0 = (tid % 16) * TN;
    int lkr = tid / 16;          // k row 0..15
    int lmc = (tid % 16) * 4;    // m col 0..60
    for (int k0 = 0; k0 < N1_; k0 += BK) {
        int k = k0 + lkr;
        const float* Sp = (k < P_) ? S_r : S_i;
        int p = (k < P_) ? k : k - P_;
        float4 av = *(const float4*)&Sp[((size_t)(b*P_ + p)) * L_ + l0 + lmc];
        float4 bv = *(const float4*)&CM[(size_t)k * H_ + n0 + lmc];
        __syncthreads();
        *(float4*)&As[lkr][lmc] = av;
        *(float4*)&Bs[lkr][lmc] = bv;
        __syncthreads();
#pragma unroll
        for (int kk = 0; kk < BK; ++kk) {
            float a[TM], bb[TN];
#pragma unroll
            for (int i = 0; i < TM; i++) a[i] = As[kk][tm0+i];
#pragma unroll
            for (int j = 0; j < TN; j++) bb[j] = Bs[kk][tn0+j];
#pragma unroll
            for (int i = 0; i < TM; i++)
#pragma unroll
                for (int j = 0; j < TN; j++)
                    acc[i][j] += a[i] * bb[j];
        }
    }
    // fused epilogue: out = acc + D*inputs   (factor 2 folded into CM)
#pragma unroll
    for (int i = 0; i < TM; i++) {
        int m = m0 + tm0 + i;
        int n = n0 + tn0;
        float4 inv = *(const float4*)&inputs[(size_t)m * H_ + n];
        float4 dv  = *(const float4*)&Dv[n];
        float4 o;
        o.x = acc[i][0] + dv.x * inv.x;
        o.y = acc[i][1] + dv.y * inv.y;
        o.z = acc[i][2] + dv.z * inv.z;
        o.w = acc[i][3] + dv.w * inv.w;
        *(float4*)&out[(size_t)m * H_ + n] = o;
    }
}

// ---------------- launch ----------------

extern "C" void kernel_launch(void* const* d_in, const int* in_sizes, int n_in,
                              void* d_out, int out_size, void* d_ws, size_t ws_size,
                              hipStream_t stream) {
    const float* inputs = (const float*)d_in[0];
    const float* lr     = (const float*)d_in[1];
    const float* li     = (const float*)d_in[2];
    const float* Bin    = (const float*)d_in[3];
    const float* Cin    = (const float*)d_in[4];
    const float* Dv     = (const float*)d_in[5];
    const float* lstep  = (const float*)d_in[6];
    float* out = (float*)d_out;

    float* ws     = (float*)d_ws;
    float* abar_r = ws;                    // 128
    float* abar_i = ws + 128;              // 128
    float* coef_r = ws + 256;              // 128
    float* coef_i = ws + 384;              // 128
    float* BT     = ws + 512;              // 512*256 = 131072
    float* CM     = BT + 131072;           // 256*512 = 131072
    float* bu_r   = CM + 131072;           // 16*128*4096 = 8388608
    float* bu_i   = bu_r + 8388608;        // 8388608
    // total ~68.2 MB of d_ws

    hipLaunchKernelGGL(precompA, dim3(1), dim3(128), 0, stream,
                       lr, li, lstep, abar_r, abar_i, coef_r, coef_i);
    hipLaunchKernelGGL(precompBT, dim3((P_*H_)/256), dim3(256), 0, stream,
                       Bin, coef_r, coef_i, BT);
    hipLaunchKernelGGL(precompCM, dim3((N1_*H_)/256), dim3(256), 0, stream,
                       Cin, CM);
    hipLaunchKernelGGL(gemm1, dim3(N1_/BN, M_/BM), dim3(256), 0, stream,
                       inputs, BT, bu_r, bu_i);
    hipLaunchKernelGGL(scan_kernel, dim3(B_*P_), dim3(256), 0, stream,
                       bu_r, bu_i, abar_r, abar_i);
    hipLaunchKernelGGL(gemm2, dim3(H_/BN, M_/BM), dim3(256), 0, stream,
                       bu_r, bu_i, CM, inputs, Dv, out);
}

// Round 3
// 280.957 us; speedup vs baseline: 1.7934x; 1.7934x over previous
//
#include <hip/hip_runtime.h>
#include <math.h>

#define B_   16
#define L_   4096
#define H_   512
#define P_   128
#define M_   (B_*L_)    // 65536
#define N2_  (2*P_)     // 256

typedef __attribute__((ext_vector_type(8))) short bf16x8;
typedef __attribute__((ext_vector_type(4))) float f32x4;

__device__ __forceinline__ unsigned short f2bf(float x) {
    unsigned u = __float_as_uint(x);
    return (unsigned short)((u + 0x7FFFu + ((u >> 16) & 1u)) >> 16);
}
__device__ __forceinline__ float bf2f(unsigned short s) {
    return __uint_as_float(((unsigned)s) << 16);
}

// ---------------- precompute ----------------

__global__ void precompA(const float* __restrict__ lr, const float* __restrict__ li,
                         const float* __restrict__ lstep,
                         float* __restrict__ abar_r, float* __restrict__ abar_i,
                         float* __restrict__ coef_r, float* __restrict__ coef_i) {
    int p = threadIdx.x;
    if (p >= P_) return;
    double lrd = (double)lr[p], lid = (double)li[p];
    double step = exp((double)lstep[p]);       // STEP_RESCALE = 1
    double ar = lrd * step, ai = lid * step;
    double ea = exp(ar);
    double abr = ea * cos(ai), abi = ea * sin(ai);
    abar_r[p] = (float)abr; abar_i[p] = (float)abi;
    double nr = abr - 1.0, ni = abi;
    double den = lrd*lrd + lid*lid;
    coef_r[p] = (float)((nr*lrd + ni*lid) / den);
    coef_i[p] = (float)((ni*lrd - nr*lid) / den);
}

// BT[n][k=h], n<128 -> Re(coef_p * B_c[p][h]) (p=n), n>=128 -> Im. bf16 hi/lo.
__global__ void precompBT(const float* __restrict__ Bin,
                          const float* __restrict__ coef_r, const float* __restrict__ coef_i,
                          unsigned short* __restrict__ BTh, unsigned short* __restrict__ BTl) {
    int idx = blockIdx.x * 256 + threadIdx.x;   // over 256*512
    if (idx >= N2_*H_) return;
    int n = idx >> 9, k = idx & 511;
    int p = n & (P_-1);
    float br = Bin[(p*H_ + k)*2 + 0], bi = Bin[(p*H_ + k)*2 + 1];
    float cr = coef_r[p], ci = coef_i[p];
    float v = (n < P_) ? (cr*br - ci*bi) : (cr*bi + ci*br);
    unsigned short h = f2bf(v);
    BTh[idx] = h;
    BTl[idx] = f2bf(v - bf2f(h));
}

// CM[n=h][k], k<128 -> 2*C_r[h][k], k>=128 -> -2*C_i[h][k-128]. bf16 hi/lo.
__global__ void precompCM(const float* __restrict__ Cin,
                          unsigned short* __restrict__ CMh, unsigned short* __restrict__ CMl) {
    int idx = blockIdx.x * 256 + threadIdx.x;   // over 512*256
    if (idx >= H_*N2_) return;
    int n = idx >> 8, k = idx & 255;
    float v;
    if (k < P_) v =  2.0f * Cin[(n*P_ + k)*2 + 0];
    else        v = -2.0f * Cin[(n*P_ + (k-P_))*2 + 1];
    unsigned short h = f2bf(v);
    CMh[idx] = h;
    CMl[idx] = f2bf(v - bf2f(h));
}

// ---------------- MFMA GEMM (hi/lo split, ~f32 accuracy) ----------------
// A: [M][K] f32 (converted to bf16 hi/lo on the fly)
// B: [N][K] bf16 hi/lo (precomputed, k-major rows)
// C: [M][N] f32, optional fused  + Dv[n]*Din[m][n]
// Tile 128x128, BK=32, 4 waves (2x2), each wave 4x4 fragments of 16x16x32.

__global__ __launch_bounds__(256) void gemm_mfma(
        const float* __restrict__ A,
        const unsigned short* __restrict__ Bh, const unsigned short* __restrict__ Bl,
        float* __restrict__ Cout, int K, int N,
        const float* __restrict__ Din, const float* __restrict__ Dv) {
    __shared__ short Ah_s[128][40];
    __shared__ short Al_s[128][40];
    __shared__ short Bh_s[128][40];
    __shared__ short Bl_s[128][40];

    int t = threadIdx.x;
    int n0 = blockIdx.x * 128;
    int m0 = blockIdx.y * 128;
    int lane = t & 63;
    int wid  = t >> 6;
    int wr = wid >> 1, wc = wid & 1;
    int lr = lane & 15, lg = lane >> 4;

    // staging indices
    int ar_ = t >> 3;            // A row 0..31 (+32 per pass)
    int ac_ = (t & 7) << 2;      // A col 0..28
    int br_ = t >> 1;            // B row 0..127
    int bc_ = (t & 1) << 4;      // B col 0 or 16 (each thread covers 16 shorts)

    f32x4 acc[4][4] = {};

    for (int k0 = 0; k0 < K; k0 += 32) {
        // global loads into regs
        float4 av[4];
#pragma unroll
        for (int i = 0; i < 4; i++)
            av[i] = *(const float4*)&A[(size_t)(m0 + ar_ + 32*i) * K + k0 + ac_];
        const unsigned short* bhp = &Bh[(size_t)(n0 + br_) * K + k0 + bc_];
        const unsigned short* blp = &Bl[(size_t)(n0 + br_) * K + k0 + bc_];
        bf16x8 bvh0 = *(const bf16x8*)bhp;
        bf16x8 bvh1 = *(const bf16x8*)(bhp + 8);
        bf16x8 bvl0 = *(const bf16x8*)blp;
        bf16x8 bvl1 = *(const bf16x8*)(blp + 8);
        __syncthreads();
#pragma unroll
        for (int i = 0; i < 4; i++) {
            float vv[4] = {av[i].x, av[i].y, av[i].z, av[i].w};
#pragma unroll
            for (int j = 0; j < 4; j++) {
                unsigned short h = f2bf(vv[j]);
                Ah_s[ar_ + 32*i][ac_ + j] = (short)h;
                Al_s[ar_ + 32*i][ac_ + j] = (short)f2bf(vv[j] - bf2f(h));
            }
        }
        *(bf16x8*)&Bh_s[br_][bc_]     = bvh0;
        *(bf16x8*)&Bh_s[br_][bc_ + 8] = bvh1;
        *(bf16x8*)&Bl_s[br_][bc_]     = bvl0;
        *(bf16x8*)&Bl_s[br_][bc_ + 8] = bvl1;
        __syncthreads();

        bf16x8 ah[4], al[4], bh[4], bl[4];
#pragma unroll
        for (int f = 0; f < 4; f++) {
            int r = wr*64 + f*16 + lr;
            ah[f] = *(bf16x8*)&Ah_s[r][lg*8];
            al[f] = *(bf16x8*)&Al_s[r][lg*8];
            int c = wc*64 + f*16 + lr;
            bh[f] = *(bf16x8*)&Bh_s[c][lg*8];
            bl[f] = *(bf16x8*)&Bl_s[c][lg*8];
        }
#pragma unroll
        for (int fm = 0; fm < 4; fm++)
#pragma unroll
            for (int fn = 0; fn < 4; fn++) {
                acc[fm][fn] = __builtin_amdgcn_mfma_f32_16x16x32_bf16(ah[fm], bh[fn], acc[fm][fn], 0, 0, 0);
                acc[fm][fn] = __builtin_amdgcn_mfma_f32_16x16x32_bf16(ah[fm], bl[fn], acc[fm][fn], 0, 0, 0);
                acc[fm][fn] = __builtin_amdgcn_mfma_f32_16x16x32_bf16(al[fm], bh[fn], acc[fm][fn], 0, 0, 0);
            }
    }

    // epilogue: C/D layout col=lane&15, row=(lane>>4)*4+reg
#pragma unroll
    for (int fm = 0; fm < 4; fm++)
#pragma unroll
        for (int fn = 0; fn < 4; fn++)
#pragma unroll
            for (int r = 0; r < 4; r++) {
                int m = m0 + wr*64 + fm*16 + lg*4 + r;
                int n = n0 + wc*64 + fn*16 + lr;
                float v = acc[fm][fn][r];
                if (Din) v += Dv[n] * Din[(size_t)m * N + n];
                Cout[(size_t)m * N + n] = v;
            }
}

// ---------------- decoupled scan over bu[b*l][256] ----------------
// chunk = 256 timesteps; 16 chunks per batch; grid (16 chunks, 16 batches)

__global__ __launch_bounds__(256) void scan_carry(const float* __restrict__ bu,
        const float* __restrict__ ar_, const float* __restrict__ ai_,
        float* __restrict__ carr) {
    __shared__ float lds[64][256];
    int t = threadIdx.x;
    int c = blockIdx.x, b = blockIdx.y;
    size_t base = ((size_t)(b*L_ + c*256)) * N2_;
    float ar = 0.f, ai = 0.f, xr = 0.f, xi = 0.f;
    if (t < 128) { ar = ar_[t]; ai = ai_[t]; }
    for (int s = 0; s < 4; s++) {
        __syncthreads();
        const float* g = bu + base + (size_t)s * 64 * N2_;
#pragma unroll
        for (int it = 0; it < 16; it++) {
            int flat = it * 1024 + t * 4;
            *(float4*)&lds[0][flat] = *(const float4*)&g[flat];
        }
        __syncthreads();
        if (t < 128) {
            for (int i = 0; i < 64; i++) {
                float br = lds[i][t], bi = lds[i][t + 128];
                float nr = ar*xr - ai*xi + br;
                float ni = ar*xi + ai*xr + bi;
                xr = nr; xi = ni;
            }
        }
    }
    if (t < 128) {
        size_t o = ((size_t)(b*16 + c)) * N2_;
        carr[o + t] = xr; carr[o + t + 128] = xi;
    }
}

__global__ void scan_chunks(const float* __restrict__ carr, float* __restrict__ pre,
                            const float* __restrict__ ar_, const float* __restrict__ ai_) {
    int id = blockIdx.x * 256 + threadIdx.x;
    if (id >= B_ * P_) return;
    int b = id >> 7, p = id & (P_-1);
    float mr = ar_[p], mi = ai_[p];
#pragma unroll
    for (int s = 0; s < 8; s++) { float tr = mr*mr - mi*mi; mi = 2.f*mr*mi; mr = tr; }  // a^256
    float xr = 0.f, xi = 0.f;
    for (int c = 0; c < 16; c++) {
        size_t o = ((size_t)(b*16 + c)) * N2_;
        pre[o + p] = xr; pre[o + p + 128] = xi;
        float cr = carr[o + p], ci = carr[o + p + 128];
        float nr = mr*xr - mi*xi + cr;
        float ni = mr*xi + mi*xr + ci;
        xr = nr; xi = ni;
    }
}

__global__ __launch_bounds__(256) void scan_apply(const float* __restrict__ bu,
        const float* __restrict__ ar_, const float* __restrict__ ai_,
        const float* __restrict__ pre, float* __restrict__ states) {
    __shared__ float lds[64][256];
    int t = threadIdx.x;
    int c = blockIdx.x, b = blockIdx.y;
    size_t base = ((size_t)(b*L_ + c*256)) * N2_;
    float ar = 0.f, ai = 0.f, xr = 0.f, xi = 0.f;
    if (t < 128) {
        ar = ar_[t]; ai = ai_[t];
        size_t o = ((size_t)(b*16 + c)) * N2_;
        xr = pre[o + t]; xi = pre[o + t + 128];
    }
    for (int s = 0; s < 4; s++) {
        __syncthreads();
        const float* g = bu + base + (size_t)s * 64 * N2_;
#pragma unroll
        for (int it = 0; it < 16; it++) {
            int flat = it * 1024 + t * 4;
            *(float4*)&lds[0][flat] = *(const float4*)&g[flat];
        }
        __syncthreads();
        if (t < 128) {
            for (int i = 0; i < 64; i++) {
                float br = lds[i][t], bi = lds[i][t + 128];
                float nr = ar*xr - ai*xi + br;
                float ni = ar*xi + ai*xr + bi;
                xr = nr; xi = ni;
                lds[i][t] = xr; lds[i][t + 128] = xi;
            }
        }
        __syncthreads();
        float* o = states + base + (size_t)s * 64 * N2_;
#pragma unroll
        for (int it = 0; it < 16; it++) {
            int flat = it * 1024 + t * 4;
            *(float4*)&o[flat] = *(const float4*)&lds[0][flat];
        }
    }
}

// ---------------- launch ----------------

extern "C" void kernel_launch(void* const* d_in, const int* in_sizes, int n_in,
                              void* d_out, int out_size, void* d_ws, size_t ws_size,
                              hipStream_t stream) {
    const float* inputs = (const float*)d_in[0];
    const float* lr     = (const float*)d_in[1];
    const float* li     = (const float*)d_in[2];
    const float* Bin    = (const float*)d_in[3];
    const float* Cin    = (const float*)d_in[4];
    const float* Dv     = (const float*)d_in[5];
    const float* lstep  = (const float*)d_in[6];
    float* out = (float*)d_out;

    // d_out doubles as scratch for bu + small buffers (all overwritten by gemm2 at the end)
    char* ob = (char*)d_out;
    float* bu = (float*)ob;                                        // 67,108,864 B
    unsigned short* BTh = (unsigned short*)(ob + 67108864);        // 262,144 B
    unsigned short* BTl = (unsigned short*)(ob + 67108864 + 262144);
    float* carr = (float*)(ob + 67108864 + 524288);                // 262,144 B
    float* pre  = (float*)(ob + 67108864 + 786432);                // 262,144 B

    float* ws     = (float*)d_ws;
    float* abar_r = ws;            // 128
    float* abar_i = ws + 128;
    float* coef_r = ws + 256;
    float* coef_i = ws + 384;
    unsigned short* CMh = (unsigned short*)(ws + 512);   // 131072 shorts
    unsigned short* CMl = CMh + H_*N2_;                  // 131072 shorts
    float* states = ws + 512 + 65536 + 65536;            // 16,777,216 f32 (~64.5 MB total ws)

    hipLaunchKernelGGL(precompA, dim3(1), dim3(128), 0, stream,
                       lr, li, lstep, abar_r, abar_i, coef_r, coef_i);
    hipLaunchKernelGGL(precompBT, dim3((N2_*H_)/256), dim3(256), 0, stream,
                       Bin, coef_r, coef_i, BTh, BTl);
    hipLaunchKernelGGL(precompCM, dim3((H_*N2_)/256), dim3(256), 0, stream,
                       Cin, CMh, CMl);
    // bu = inputs @ BT^T   (M x 512)*(512 x 256)
    hipLaunchKernelGGL(gemm_mfma, dim3(N2_/128, M_/128), dim3(256), 0, stream,
                       inputs, BTh, BTl, bu, H_, N2_, (const float*)nullptr, (const float*)nullptr);
    hipLaunchKernelGGL(scan_carry, dim3(16, B_), dim3(256), 0, stream,
                       bu, abar_r, abar_i, carr);
    hipLaunchKernelGGL(scan_chunks, dim3(8), dim3(256), 0, stream,
                       carr, pre, abar_r, abar_i);
    hipLaunchKernelGGL(scan_apply, dim3(16, B_), dim3(256), 0, stream,
                       bu, abar_r, abar_i, pre, states);
    // out = states @ CM^T + D*inputs   (M x 256)*(256 x 512)
    hipLaunchKernelGGL(gemm_mfma, dim3(H_/128, M_/128), dim3(256), 0, stream,
                       states, CMh, CMl, out, N2_, H_, inputs, Dv);
}

// Round 4
// 276.441 us; speedup vs baseline: 1.8227x; 1.0163x over previous
//
#include <hip/hip_runtime.h>
#include <math.h>

#define B_   16
#define L_   4096
#define H_   512
#define P_   128
#define M_   (B_*L_)    // 65536
#define N2_  (2*P_)     // 256

typedef __attribute__((ext_vector_type(8))) short bf16x8;
typedef __attribute__((ext_vector_type(8))) unsigned short u16x8;
typedef __attribute__((ext_vector_type(4))) float f32x4;

__device__ __forceinline__ unsigned short f2bf(float x) {
    unsigned u = __float_as_uint(x);
    return (unsigned short)((u + 0x7FFFu + ((u >> 16) & 1u)) >> 16);
}
__device__ __forceinline__ float bf2f(unsigned short s) {
    return __uint_as_float(((unsigned)s) << 16);
}

__device__ __forceinline__ void gload16(const void* g, void* l) {
    __builtin_amdgcn_global_load_lds(
        (const __attribute__((address_space(1))) void*)g,
        (__attribute__((address_space(3))) void*)l,
        16, 0, 0);
}

// ---------------- precompute ----------------

__global__ void precompA(const float* __restrict__ lr, const float* __restrict__ li,
                         const float* __restrict__ lstep,
                         float* __restrict__ abar_r, float* __restrict__ abar_i,
                         float* __restrict__ coef_r, float* __restrict__ coef_i) {
    int p = threadIdx.x;
    if (p >= P_) return;
    double lrd = (double)lr[p], lid = (double)li[p];
    double step = exp((double)lstep[p]);       // STEP_RESCALE = 1
    double ar = lrd * step, ai = lid * step;
    double ea = exp(ar);
    double abr = ea * cos(ai), abi = ea * sin(ai);
    abar_r[p] = (float)abr; abar_i[p] = (float)abi;
    double nr = abr - 1.0, ni = abi;
    double den = lrd*lrd + lid*lid;
    coef_r[p] = (float)((nr*lrd + ni*lid) / den);
    coef_i[p] = (float)((ni*lrd - nr*lid) / den);
}

// BT[n][k=h]: n<128 -> Re(coef_p * B_c[p][h]), n>=128 -> Im. bf16 hi/lo.
__global__ void precompBT(const float* __restrict__ Bin,
                          const float* __restrict__ coef_r, const float* __restrict__ coef_i,
                          unsigned short* __restrict__ BTh, unsigned short* __restrict__ BTl) {
    int idx = blockIdx.x * 256 + threadIdx.x;   // over 256*512
    if (idx >= N2_*H_) return;
    int n = idx >> 9, k = idx & 511;
    int p = n & (P_-1);
    float br = Bin[(p*H_ + k)*2 + 0], bi = Bin[(p*H_ + k)*2 + 1];
    float cr = coef_r[p], ci = coef_i[p];
    float v = (n < P_) ? (cr*br - ci*bi) : (cr*bi + ci*br);
    unsigned short h = f2bf(v);
    BTh[idx] = h;
    BTl[idx] = f2bf(v - bf2f(h));
}

// CM[n=h][k]: k<128 -> 2*C_r[h][k], k>=128 -> -2*C_i[h][k-128]. bf16 hi/lo.
__global__ void precompCM(const float* __restrict__ Cin,
                          unsigned short* __restrict__ CMh, unsigned short* __restrict__ CMl) {
    int idx = blockIdx.x * 256 + threadIdx.x;   // over 512*256
    if (idx >= H_*N2_) return;
    int n = idx >> 8, k = idx & 255;
    float v;
    if (k < P_) v =  2.0f * Cin[(n*P_ + k)*2 + 0];
    else        v = -2.0f * Cin[(n*P_ + (k-P_))*2 + 1];
    unsigned short h = f2bf(v);
    CMh[idx] = h;
    CMl[idx] = f2bf(v - bf2f(h));
}

// ---------------- f32 -> bf16(hi) conversion pass ----------------

__global__ __launch_bounds__(256) void conv_hi(const float* __restrict__ x,
                                               unsigned short* __restrict__ y) {
    size_t i = ((size_t)blockIdx.x * 256 + threadIdx.x) * 8;
    float4 a = *(const float4*)&x[i];
    float4 b = *(const float4*)&x[i + 4];
    u16x8 o;
    o[0] = f2bf(a.x); o[1] = f2bf(a.y); o[2] = f2bf(a.z); o[3] = f2bf(a.w);
    o[4] = f2bf(b.x); o[5] = f2bf(b.y); o[6] = f2bf(b.z); o[7] = f2bf(b.w);
    *(u16x8*)&y[i] = o;
}

// ---------------- MFMA GEMM: C = A(bf16) @ [Bh+Bl]^T (+ D*Din) ----------------
// A: [M][K] bf16 row-major. Bh/Bl: [N][K] bf16 (k-major rows).
// 128x128 tile, BK=64, 4 waves (2x2), 4x4 frags of 16x16x32, 2 MFMA per pair.
// LDS: linear layout, XOR-swizzled (slot ^= row&7) via pre-swizzled global src.

template<int KSTEPS>
__global__ __launch_bounds__(256) void gemm_bf16(
        const unsigned short* __restrict__ A,
        const unsigned short* __restrict__ Bh, const unsigned short* __restrict__ Bl,
        float* __restrict__ Cout, int N,
        const float* __restrict__ Din, const float* __restrict__ Dv) {
    constexpr int K = KSTEPS * 64;
    __shared__ unsigned short As [128 * 64];
    __shared__ unsigned short Bhs[128 * 64];
    __shared__ unsigned short Bls[128 * 64];

    int t = threadIdx.x;
    int n0 = blockIdx.x * 128;
    int m0 = blockIdx.y * 128;
    int lane = t & 63;
    int w    = t >> 6;
    int wr = w >> 1, wc = w & 1;
    int lr = lane & 15, lg = lane >> 4;

    // staging: issue covers 32 rows x 64 k (4KB); thread t -> row t>>3, slot t&7.
    // LDS[row][slot] = G[row][slot ^ (row&7)]  (linear LDS dest, swizzled source)
    int tr = t >> 3;                      // 0..31
    int ss = (t & 7) ^ (tr & 7);          // swizzled source slot
    const unsigned short* gA  = A  + (size_t)(m0 + tr) * K + ss * 8;
    const unsigned short* gBh = Bh + (size_t)(n0 + tr) * K + ss * 8;
    const unsigned short* gBl = Bl + (size_t)(n0 + tr) * K + ss * 8;
    unsigned short* lA  = As  + w * 512;   // wave-uniform base; +2048 elems per issue
    unsigned short* lBh = Bhs + w * 512;
    unsigned short* lBl = Bls + w * 512;

    f32x4 acc[4][4] = {};

    for (int kstep = 0; kstep < KSTEPS; ++kstep) {
        int k0 = kstep * 64;
        __syncthreads();
#pragma unroll
        for (int is = 0; is < 4; ++is) {
            gload16(gA  + (size_t)is * 32 * K + k0, lA  + is * 2048);
            gload16(gBh + (size_t)is * 32 * K + k0, lBh + is * 2048);
            gload16(gBl + (size_t)is * 32 * K + k0, lBl + is * 2048);
        }
        __syncthreads();

#pragma unroll
        for (int ku = 0; ku < 2; ++ku) {
            int slot = (((lg + ku * 4) ^ (lr & 7)) << 3);
            bf16x8 af[4], bhf[4], blf[4];
#pragma unroll
            for (int f = 0; f < 4; ++f) {
                af[f]  = *(const bf16x8*)&As [(wr * 64 + f * 16 + lr) * 64 + slot];
                bhf[f] = *(const bf16x8*)&Bhs[(wc * 64 + f * 16 + lr) * 64 + slot];
                blf[f] = *(const bf16x8*)&Bls[(wc * 64 + f * 16 + lr) * 64 + slot];
            }
#pragma unroll
            for (int fm = 0; fm < 4; ++fm)
#pragma unroll
                for (int fn = 0; fn < 4; ++fn) {
                    acc[fm][fn] = __builtin_amdgcn_mfma_f32_16x16x32_bf16(af[fm], bhf[fn], acc[fm][fn], 0, 0, 0);
                    acc[fm][fn] = __builtin_amdgcn_mfma_f32_16x16x32_bf16(af[fm], blf[fn], acc[fm][fn], 0, 0, 0);
                }
        }
    }

    // epilogue: C/D layout col=lane&15, row=(lane>>4)*4+reg
#pragma unroll
    for (int fm = 0; fm < 4; ++fm)
#pragma unroll
        for (int fn = 0; fn < 4; ++fn)
#pragma unroll
            for (int r = 0; r < 4; ++r) {
                int m = m0 + wr * 64 + fm * 16 + lg * 4 + r;
                int n = n0 + wc * 64 + fn * 16 + lr;
                float v = acc[fm][fn][r];
                if (Din) v += Dv[n] * Din[(size_t)m * N + n];
                Cout[(size_t)m * N + n] = v;
            }
}

// ---------------- decoupled scan over bu[b*l][256] ----------------

__global__ __launch_bounds__(256) void scan_carry(const float* __restrict__ bu,
        const float* __restrict__ ar_, const float* __restrict__ ai_,
        float* __restrict__ carr) {
    __shared__ float lds[64][256];
    int t = threadIdx.x;
    int c = blockIdx.x, b = blockIdx.y;
    size_t base = ((size_t)(b*L_ + c*256)) * N2_;
    float ar = 0.f, ai = 0.f, xr = 0.f, xi = 0.f;
    if (t < 128) { ar = ar_[t]; ai = ai_[t]; }
    for (int s = 0; s < 4; s++) {
        __syncthreads();
        const float* g = bu + base + (size_t)s * 64 * N2_;
#pragma unroll
        for (int it = 0; it < 16; it++) {
            int flat = it * 1024 + t * 4;
            *(float4*)&lds[0][flat] = *(const float4*)&g[flat];
        }
        __syncthreads();
        if (t < 128) {
            for (int i = 0; i < 64; i++) {
                float br = lds[i][t], bi = lds[i][t + 128];
                float nr = ar*xr - ai*xi + br;
                float ni = ar*xi + ai*xr + bi;
                xr = nr; xi = ni;
            }
        }
    }
    if (t < 128) {
        size_t o = ((size_t)(b*16 + c)) * N2_;
        carr[o + t] = xr; carr[o + t + 128] = xi;
    }
}

__global__ void scan_chunks(const float* __restrict__ carr, float* __restrict__ pre,
                            const float* __restrict__ ar_, const float* __restrict__ ai_) {
    int id = blockIdx.x * 256 + threadIdx.x;
    if (id >= B_ * P_) return;
    int b = id >> 7, p = id & (P_-1);
    float mr = ar_[p], mi = ai_[p];
#pragma unroll
    for (int s = 0; s < 8; s++) { float tr = mr*mr - mi*mi; mi = 2.f*mr*mi; mr = tr; }  // a^256
    float xr = 0.f, xi = 0.f;
    for (int c = 0; c < 16; c++) {
        size_t o = ((size_t)(b*16 + c)) * N2_;
        pre[o + p] = xr; pre[o + p + 128] = xi;
        float cr = carr[o + p], ci = carr[o + p + 128];
        float nr = mr*xr - mi*xi + cr;
        float ni = mr*xi + mi*xr + ci;
        xr = nr; xi = ni;
    }
}

// scan_apply: states emitted as bf16(hi) [m][256] for gemm2's MFMA A-operand
__global__ __launch_bounds__(256) void scan_apply(const float* __restrict__ bu,
        const float* __restrict__ ar_, const float* __restrict__ ai_,
        const float* __restrict__ pre, unsigned short* __restrict__ states_h) {
    __shared__ float lds[64][256];
    int t = threadIdx.x;
    int c = blockIdx.x, b = blockIdx.y;
    size_t base = ((size_t)(b*L_ + c*256)) * N2_;
    float ar = 0.f, ai = 0.f, xr = 0.f, xi = 0.f;
    if (t < 128) {
        ar = ar_[t]; ai = ai_[t];
        size_t o = ((size_t)(b*16 + c)) * N2_;
        xr = pre[o + t]; xi = pre[o + t + 128];
    }
    for (int s = 0; s < 4; s++) {
        __syncthreads();
        const float* g = bu + base + (size_t)s * 64 * N2_;
#pragma unroll
        for (int it = 0; it < 16; it++) {
            int flat = it * 1024 + t * 4;
            *(float4*)&lds[0][flat] = *(const float4*)&g[flat];
        }
        __syncthreads();
        if (t < 128) {
            for (int i = 0; i < 64; i++) {
                float br = lds[i][t], bi = lds[i][t + 128];
                float nr = ar*xr - ai*xi + br;
                float ni = ar*xi + ai*xr + bi;
                xr = nr; xi = ni;
                lds[i][t] = xr; lds[i][t + 128] = xi;
            }
        }
        __syncthreads();
        unsigned short* o = states_h + base + (size_t)s * 64 * N2_;
#pragma unroll
        for (int it = 0; it < 8; it++) {
            int flat = it * 2048 + t * 8;
            float4 v0 = *(const float4*)&lds[0][flat];
            float4 v1 = *(const float4*)&lds[0][flat + 4];
            u16x8 ov;
            ov[0] = f2bf(v0.x); ov[1] = f2bf(v0.y); ov[2] = f2bf(v0.z); ov[3] = f2bf(v0.w);
            ov[4] = f2bf(v1.x); ov[5] = f2bf(v1.y); ov[6] = f2bf(v1.z); ov[7] = f2bf(v1.w);
            *(u16x8*)&o[flat] = ov;
        }
    }
}

// ---------------- launch ----------------

extern "C" void kernel_launch(void* const* d_in, const int* in_sizes, int n_in,
                              void* d_out, int out_size, void* d_ws, size_t ws_size,
                              hipStream_t stream) {
    const float* inputs = (const float*)d_in[0];
    const float* lr     = (const float*)d_in[1];
    const float* li     = (const float*)d_in[2];
    const float* Bin    = (const float*)d_in[3];
    const float* Cin    = (const float*)d_in[4];
    const float* Dv     = (const float*)d_in[5];
    const float* lstep  = (const float*)d_in[6];
    float* out = (float*)d_out;

    // d_out as scratch: bu f32 (67.1MB) | Ah bf16 (67.1MB). Fully overwritten by gemm2.
    char* ob = (char*)d_out;
    float*          bu = (float*)ob;
    unsigned short* Ah = (unsigned short*)(ob + 67108864);

    // d_ws (~35.7MB of proven 68MB): consts | carr | pre | BTh BTl CMh CMl | states_h
    float* ws     = (float*)d_ws;
    float* abar_r = ws;
    float* abar_i = ws + 128;
    float* coef_r = ws + 256;
    float* coef_i = ws + 384;
    float* carr   = ws + 512;            // 65536 f32
    float* pre    = ws + 66048;          // 65536 f32
    unsigned short* BTh = (unsigned short*)(ws + 131584);   // 131072 u16 each
    unsigned short* BTl = BTh + N2_*H_;
    unsigned short* CMh = BTl + N2_*H_;
    unsigned short* CMl = CMh + H_*N2_;
    unsigned short* states_h = CMl + H_*N2_;                // 16,777,216 u16

    hipLaunchKernelGGL(precompA, dim3(1), dim3(128), 0, stream,
                       lr, li, lstep, abar_r, abar_i, coef_r, coef_i);
    hipLaunchKernelGGL(precompBT, dim3((N2_*H_)/256), dim3(256), 0, stream,
                       Bin, coef_r, coef_i, BTh, BTl);
    hipLaunchKernelGGL(precompCM, dim3((H_*N2_)/256), dim3(256), 0, stream,
                       Cin, CMh, CMl);
    hipLaunchKernelGGL(conv_hi, dim3((M_*H_)/(256*8)), dim3(256), 0, stream,
                       inputs, Ah);
    // bu = Ah @ BT^T   (65536 x 512)*(512 x 256)
    hipLaunchKernelGGL((gemm_bf16<8>), dim3(N2_/128, M_/128), dim3(256), 0, stream,
                       Ah, BTh, BTl, bu, N2_, (const float*)nullptr, (const float*)nullptr);
    hipLaunchKernelGGL(scan_carry, dim3(16, B_), dim3(256), 0, stream,
                       bu, abar_r, abar_i, carr);
    hipLaunchKernelGGL(scan_chunks, dim3(8), dim3(256), 0, stream,
                       carr, pre, abar_r, abar_i);
    hipLaunchKernelGGL(scan_apply, dim3(16, B_), dim3(256), 0, stream,
                       bu, abar_r, abar_i, pre, states_h);
    // out = states @ CM^T + D*inputs   (65536 x 256)*(256 x 512)
    hipLaunchKernelGGL((gemm_bf16<4>), dim3(H_/128, M_/128), dim3(256), 0, stream,
                       states_h, CMh, CMl, out, H_, inputs, Dv);
}

// Round 5
// 253.245 us; speedup vs baseline: 1.9897x; 1.0916x over previous
//
#include <hip/hip_runtime.h>
#include <math.h>

#define B_   16
#define L_   4096
#define H_   512
#define P_   128
#define M_   (B_*L_)    // 65536
#define N2_  (2*P_)     // 256

typedef __attribute__((ext_vector_type(8))) short bf16x8;
typedef __attribute__((ext_vector_type(8))) unsigned short u16x8;
typedef __attribute__((ext_vector_type(4))) float f32x4;

__device__ __forceinline__ unsigned short f2bf(float x) {
    unsigned u = __float_as_uint(x);
    return (unsigned short)((u + 0x7FFFu + ((u >> 16) & 1u)) >> 16);
}
__device__ __forceinline__ float bf2f(unsigned short s) {
    return __uint_as_float(((unsigned)s) << 16);
}

__device__ __forceinline__ void gload16(const void* g, void* l) {
    __builtin_amdgcn_global_load_lds(
        (const __attribute__((address_space(1))) void*)g,
        (__attribute__((address_space(3))) void*)l,
        16, 0, 0);
}

// ---------------- precompute ----------------

__global__ void precompA(const float* __restrict__ lr, const float* __restrict__ li,
                         const float* __restrict__ lstep,
                         float* __restrict__ abar_r, float* __restrict__ abar_i,
                         float* __restrict__ coef_r, float* __restrict__ coef_i) {
    int p = threadIdx.x;
    if (p >= P_) return;
    double lrd = (double)lr[p], lid = (double)li[p];
    double step = exp((double)lstep[p]);       // STEP_RESCALE = 1
    double ar = lrd * step, ai = lid * step;
    double ea = exp(ar);
    double abr = ea * cos(ai), abi = ea * sin(ai);
    abar_r[p] = (float)abr; abar_i[p] = (float)abi;
    double nr = abr - 1.0, ni = abi;
    double den = lrd*lrd + lid*lid;
    coef_r[p] = (float)((nr*lrd + ni*lid) / den);
    coef_i[p] = (float)((ni*lrd - nr*lid) / den);
}

// BT[n][k=h]: n<128 -> Re(coef_p * B_c[p][h]), n>=128 -> Im. bf16 (round-nearest).
__global__ void precompBT(const float* __restrict__ Bin,
                          const float* __restrict__ coef_r, const float* __restrict__ coef_i,
                          unsigned short* __restrict__ BTh) {
    int idx = blockIdx.x * 256 + threadIdx.x;   // over 256*512
    if (idx >= N2_*H_) return;
    int n = idx >> 9, k = idx & 511;
    int p = n & (P_-1);
    float br = Bin[(p*H_ + k)*2 + 0], bi = Bin[(p*H_ + k)*2 + 1];
    float cr = coef_r[p], ci = coef_i[p];
    float v = (n < P_) ? (cr*br - ci*bi) : (cr*bi + ci*br);
    BTh[idx] = f2bf(v);
}

// CM[n=h][k]: k<128 -> 2*C_r[h][k], k>=128 -> -2*C_i[h][k-128]. bf16.
__global__ void precompCM(const float* __restrict__ Cin,
                          unsigned short* __restrict__ CMh) {
    int idx = blockIdx.x * 256 + threadIdx.x;   // over 512*256
    if (idx >= H_*N2_) return;
    int n = idx >> 8, k = idx & 255;
    float v;
    if (k < P_) v =  2.0f * Cin[(n*P_ + k)*2 + 0];
    else        v = -2.0f * Cin[(n*P_ + (k-P_))*2 + 1];
    CMh[idx] = f2bf(v);
}

// ---------------- f32 -> bf16 conversion pass ----------------

__global__ __launch_bounds__(256) void conv_hi(const float* __restrict__ x,
                                               unsigned short* __restrict__ y) {
    size_t i = ((size_t)blockIdx.x * 256 + threadIdx.x) * 8;
    float4 a = *(const float4*)&x[i];
    float4 b = *(const float4*)&x[i + 4];
    u16x8 o;
    o[0] = f2bf(a.x); o[1] = f2bf(a.y); o[2] = f2bf(a.z); o[3] = f2bf(a.w);
    o[4] = f2bf(b.x); o[5] = f2bf(b.y); o[6] = f2bf(b.z); o[7] = f2bf(b.w);
    *(u16x8*)&y[i] = o;
}

// ---------------- MFMA GEMM: C = A(bf16) @ B^T (+ D*Din) ----------------
// A: [M][K] bf16. B: [N][K] bf16 (k-major rows).
// 128x128 tile, BK=64, 4 waves (2x2), 4x4 frags of 16x16x32.
// 2-phase double-buffered: {barrier -> stage(next) -> ds_read+MFMA(cur)}.
// LDS XOR-swizzled (slot ^= row&7) via pre-swizzled global source (rule #21).

template<int KSTEPS>
__global__ __launch_bounds__(256) void gemm_bf16(
        const unsigned short* __restrict__ A,
        const unsigned short* __restrict__ Bm,
        float* __restrict__ Cout, int N,
        const float* __restrict__ Din, const float* __restrict__ Dv) {
    constexpr int K = KSTEPS * 64;
    __shared__ unsigned short As[2][128 * 64];
    __shared__ unsigned short Bs[2][128 * 64];

    int t = threadIdx.x;
    // XCD-aware swizzle: contiguous chunk of flat ids per XCD (nwg % 8 == 0)
    int nx = gridDim.x;                       // 2 (gemm1) or 4 (gemm2), pow2
    int flat = blockIdx.x + nx * blockIdx.y;
    int per  = (nx * gridDim.y) >> 3;
    int nid  = (flat & 7) * per + (flat >> 3);
    int n0 = (nid & (nx - 1)) * 128;
    int m0 = (nid / nx) * 128;

    int lane = t & 63;
    int w    = t >> 6;
    int wr = w >> 1, wc = w & 1;
    int lr = lane & 15, lg = lane >> 4;

    // staging: thread t -> row t>>3 (0..31), slot t&7; source slot XOR-swizzled.
    int tr = t >> 3;
    int ss = (t & 7) ^ (tr & 7);
    const unsigned short* gA = A  + (size_t)(m0 + tr) * K + ss * 8;
    const unsigned short* gB = Bm + (size_t)(n0 + tr) * K + ss * 8;
    int ldst = w * 512;                        // wave-uniform base (elems)

    f32x4 acc[4][4] = {};

    // prologue: stage K-step 0 into buf 0
#pragma unroll
    for (int is = 0; is < 4; ++is) {
        gload16(gA + (size_t)is * 32 * K, &As[0][ldst + is * 2048]);
        gload16(gB + (size_t)is * 32 * K, &Bs[0][ldst + is * 2048]);
    }

    for (int ks = 0; ks < KSTEPS; ++ks) {
        __syncthreads();                       // drains vmcnt -> buf[ks&1] ready
        int cur = ks & 1;
        if (ks + 1 < KSTEPS) {
            int k1 = (ks + 1) * 64;
#pragma unroll
            for (int is = 0; is < 4; ++is) {
                gload16(gA + (size_t)is * 32 * K + k1, &As[cur ^ 1][ldst + is * 2048]);
                gload16(gB + (size_t)is * 32 * K + k1, &Bs[cur ^ 1][ldst + is * 2048]);
            }
        }
#pragma unroll
        for (int ku = 0; ku < 2; ++ku) {
            int slot = (((lg + ku * 4) ^ (lr & 7)) << 3);
            bf16x8 af[4], bf[4];
#pragma unroll
            for (int f = 0; f < 4; ++f) {
                af[f] = *(const bf16x8*)&As[cur][(wr * 64 + f * 16 + lr) * 64 + slot];
                bf[f] = *(const bf16x8*)&Bs[cur][(wc * 64 + f * 16 + lr) * 64 + slot];
            }
#pragma unroll
            for (int fm = 0; fm < 4; ++fm)
#pragma unroll
                for (int fn = 0; fn < 4; ++fn)
                    acc[fm][fn] = __builtin_amdgcn_mfma_f32_16x16x32_bf16(af[fm], bf[fn], acc[fm][fn], 0, 0, 0);
        }
    }

    // epilogue: C/D layout col=lane&15, row=(lane>>4)*4+reg
#pragma unroll
    for (int fm = 0; fm < 4; ++fm)
#pragma unroll
        for (int fn = 0; fn < 4; ++fn)
#pragma unroll
            for (int r = 0; r < 4; ++r) {
                int m = m0 + wr * 64 + fm * 16 + lg * 4 + r;
                int n = n0 + wc * 64 + fn * 16 + lr;
                float v = acc[fm][fn][r];
                if (Din) v += Dv[n] * Din[(size_t)m * N + n];
                Cout[(size_t)m * N + n] = v;
            }
}

// ---------------- decoupled scan over bu[b*l][256] ----------------

__global__ __launch_bounds__(256) void scan_carry(const float* __restrict__ bu,
        const float* __restrict__ ar_, const float* __restrict__ ai_,
        float* __restrict__ carr) {
    __shared__ float lds[64][256];
    int t = threadIdx.x;
    int c = blockIdx.x, b = blockIdx.y;
    size_t base = ((size_t)(b*L_ + c*256)) * N2_;
    float ar = 0.f, ai = 0.f, xr = 0.f, xi = 0.f;
    if (t < 128) { ar = ar_[t]; ai = ai_[t]; }
    for (int s = 0; s < 4; s++) {
        __syncthreads();
        const float* g = bu + base + (size_t)s * 64 * N2_;
#pragma unroll
        for (int it = 0; it < 16; it++) {
            int flat = it * 1024 + t * 4;
            *(float4*)&lds[0][flat] = *(const float4*)&g[flat];
        }
        __syncthreads();
        if (t < 128) {
            for (int i = 0; i < 64; i++) {
                float br = lds[i][t], bi = lds[i][t + 128];
                float nr = ar*xr - ai*xi + br;
                float ni = ar*xi + ai*xr + bi;
                xr = nr; xi = ni;
            }
        }
    }
    if (t < 128) {
        size_t o = ((size_t)(b*16 + c)) * N2_;
        carr[o + t] = xr; carr[o + t + 128] = xi;
    }
}

__global__ void scan_chunks(const float* __restrict__ carr, float* __restrict__ pre,
                            const float* __restrict__ ar_, const float* __restrict__ ai_) {
    int id = blockIdx.x * 256 + threadIdx.x;
    if (id >= B_ * P_) return;
    int b = id >> 7, p = id & (P_-1);
    float mr = ar_[p], mi = ai_[p];
#pragma unroll
    for (int s = 0; s < 8; s++) { float tr = mr*mr - mi*mi; mi = 2.f*mr*mi; mr = tr; }  // a^256
    float xr = 0.f, xi = 0.f;
    for (int c = 0; c < 16; c++) {
        size_t o = ((size_t)(b*16 + c)) * N2_;
        pre[o + p] = xr; pre[o + p + 128] = xi;
        float cr = carr[o + p], ci = carr[o + p + 128];
        float nr = mr*xr - mi*xi + cr;
        float ni = mr*xi + mi*xr + ci;
        xr = nr; xi = ni;
    }
}

// scan_apply: states emitted as bf16 [m][256] for gemm2's MFMA A-operand
__global__ __launch_bounds__(256) void scan_apply(const float* __restrict__ bu,
        const float* __restrict__ ar_, const float* __restrict__ ai_,
        const float* __restrict__ pre, unsigned short* __restrict__ states_h) {
    __shared__ float lds[64][256];
    int t = threadIdx.x;
    int c = blockIdx.x, b = blockIdx.y;
    size_t base = ((size_t)(b*L_ + c*256)) * N2_;
    float ar = 0.f, ai = 0.f, xr = 0.f, xi = 0.f;
    if (t < 128) {
        ar = ar_[t]; ai = ai_[t];
        size_t o = ((size_t)(b*16 + c)) * N2_;
        xr = pre[o + t]; xi = pre[o + t + 128];
    }
    for (int s = 0; s < 4; s++) {
        __syncthreads();
        const float* g = bu + base + (size_t)s * 64 * N2_;
#pragma unroll
        for (int it = 0; it < 16; it++) {
            int flat = it * 1024 + t * 4;
            *(float4*)&lds[0][flat] = *(const float4*)&g[flat];
        }
        __syncthreads();
        if (t < 128) {
            for (int i = 0; i < 64; i++) {
                float br = lds[i][t], bi = lds[i][t + 128];
                float nr = ar*xr - ai*xi + br;
                float ni = ar*xi + ai*xr + bi;
                xr = nr; xi = ni;
                lds[i][t] = xr; lds[i][t + 128] = xi;
            }
        }
        __syncthreads();
        unsigned short* o = states_h + base + (size_t)s * 64 * N2_;
#pragma unroll
        for (int it = 0; it < 8; it++) {
            int flat = it * 2048 + t * 8;
            float4 v0 = *(const float4*)&lds[0][flat];
            float4 v1 = *(const float4*)&lds[0][flat + 4];
            u16x8 ov;
            ov[0] = f2bf(v0.x); ov[1] = f2bf(v0.y); ov[2] = f2bf(v0.z); ov[3] = f2bf(v0.w);
            ov[4] = f2bf(v1.x); ov[5] = f2bf(v1.y); ov[6] = f2bf(v1.z); ov[7] = f2bf(v1.w);
            *(u16x8*)&o[flat] = ov;
        }
    }
}

// ---------------- launch ----------------

extern "C" void kernel_launch(void* const* d_in, const int* in_sizes, int n_in,
                              void* d_out, int out_size, void* d_ws, size_t ws_size,
                              hipStream_t stream) {
    const float* inputs = (const float*)d_in[0];
    const float* lr     = (const float*)d_in[1];
    const float* li     = (const float*)d_in[2];
    const float* Bin    = (const float*)d_in[3];
    const float* Cin    = (const float*)d_in[4];
    const float* Dv     = (const float*)d_in[5];
    const float* lstep  = (const float*)d_in[6];
    float* out = (float*)d_out;

    // d_out as scratch: bu f32 (64MB) | Ah bf16 (64MB). Fully overwritten by gemm2.
    char* ob = (char*)d_out;
    float*          bu = (float*)ob;
    unsigned short* Ah = (unsigned short*)(ob + 67108864);

    // d_ws (~34.6MB of proven 68MB)
    float* ws     = (float*)d_ws;
    float* abar_r = ws;
    float* abar_i = ws + 128;
    float* coef_r = ws + 256;
    float* coef_i = ws + 384;
    float* carr   = ws + 512;            // 65536 f32
    float* pre    = ws + 66048;          // 65536 f32
    unsigned short* BTh = (unsigned short*)(ws + 131584);   // 131072 u16
    unsigned short* CMh = BTh + N2_*H_;                     // 131072 u16
    unsigned short* states_h = CMh + H_*N2_;                // 16,777,216 u16

    hipLaunchKernelGGL(precompA, dim3(1), dim3(128), 0, stream,
                       lr, li, lstep, abar_r, abar_i, coef_r, coef_i);
    hipLaunchKernelGGL(precompBT, dim3((N2_*H_)/256), dim3(256), 0, stream,
                       Bin, coef_r, coef_i, BTh);
    hipLaunchKernelGGL(precompCM, dim3((H_*N2_)/256), dim3(256), 0, stream,
                       Cin, CMh);
    hipLaunchKernelGGL(conv_hi, dim3((M_*H_)/(256*8)), dim3(256), 0, stream,
                       inputs, Ah);
    // bu = Ah @ BT^T   (65536 x 512)*(512 x 256)
    hipLaunchKernelGGL((gemm_bf16<8>), dim3(N2_/128, M_/128), dim3(256), 0, stream,
                       Ah, BTh, bu, N2_, (const float*)nullptr, (const float*)nullptr);
    hipLaunchKernelGGL(scan_carry, dim3(16, B_), dim3(256), 0, stream,
                       bu, abar_r, abar_i, carr);
    hipLaunchKernelGGL(scan_chunks, dim3(8), dim3(256), 0, stream,
                       carr, pre, abar_r, abar_i);
    hipLaunchKernelGGL(scan_apply, dim3(16, B_), dim3(256), 0, stream,
                       bu, abar_r, abar_i, pre, states_h);
    // out = states @ CM^T + D*inputs   (65536 x 256)*(256 x 512)
    hipLaunchKernelGGL((gemm_bf16<4>), dim3(H_/128, M_/128), dim3(256), 0, stream,
                       states_h, CMh, out, H_, inputs, Dv);
}

// Round 7
// 252.453 us; speedup vs baseline: 1.9959x; 1.0031x over previous
//
#include <hip/hip_runtime.h>
#include <math.h>

#define B_   16
#define L_   4096
#define H_   512
#define P_   128
#define M_   (B_*L_)    // 65536
#define N2_  (2*P_)     // 256

typedef __attribute__((ext_vector_type(8))) short bf16x8;
typedef __attribute__((ext_vector_type(8))) unsigned short u16x8;
typedef __attribute__((ext_vector_type(4))) float f32x4;

__device__ __forceinline__ unsigned short f2bf(float x) {
    unsigned u = __float_as_uint(x);
    return (unsigned short)((u + 0x7FFFu + ((u >> 16) & 1u)) >> 16);
}
__device__ __forceinline__ float bf2f(unsigned short s) {
    return __uint_as_float(((unsigned)s) << 16);
}

__device__ __forceinline__ void gload16(const void* g, void* l) {
    __builtin_amdgcn_global_load_lds(
        (const __attribute__((address_space(1))) void*)g,
        (__attribute__((address_space(3))) void*)l,
        16, 0, 0);
}

// ---------------- precompute ----------------

__global__ void precompA(const float* __restrict__ lr, const float* __restrict__ li,
                         const float* __restrict__ lstep,
                         float* __restrict__ abar_r, float* __restrict__ abar_i,
                         float* __restrict__ coef_r, float* __restrict__ coef_i) {
    int p = threadIdx.x;
    if (p >= P_) return;
    double lrd = (double)lr[p], lid = (double)li[p];
    double step = exp((double)lstep[p]);       // STEP_RESCALE = 1
    double ar = lrd * step, ai = lid * step;
    double ea = exp(ar);
    double abr = ea * cos(ai), abi = ea * sin(ai);
    abar_r[p] = (float)abr; abar_i[p] = (float)abi;
    double nr = abr - 1.0, ni = abi;
    double den = lrd*lrd + lid*lid;
    coef_r[p] = (float)((nr*lrd + ni*lid) / den);
    coef_i[p] = (float)((ni*lrd - nr*lid) / den);
}

// BT[n][k=h]: n<128 -> Re(coef_p * B_c[p][h]), n>=128 -> Im. bf16.
__global__ void precompBT(const float* __restrict__ Bin,
                          const float* __restrict__ coef_r, const float* __restrict__ coef_i,
                          unsigned short* __restrict__ BTh) {
    int idx = blockIdx.x * 256 + threadIdx.x;   // over 256*512
    if (idx >= N2_*H_) return;
    int n = idx >> 9, k = idx & 511;
    int p = n & (P_-1);
    float br = Bin[(p*H_ + k)*2 + 0], bi = Bin[(p*H_ + k)*2 + 1];
    float cr = coef_r[p], ci = coef_i[p];
    float v = (n < P_) ? (cr*br - ci*bi) : (cr*bi + ci*br);
    BTh[idx] = f2bf(v);
}

// CM[n=h][k]: k<128 -> 2*C_r[h][k], k>=128 -> -2*C_i[h][k-128]. bf16.
__global__ void precompCM(const float* __restrict__ Cin,
                          unsigned short* __restrict__ CMh) {
    int idx = blockIdx.x * 256 + threadIdx.x;   // over 512*256
    if (idx >= H_*N2_) return;
    int n = idx >> 8, k = idx & 255;
    float v;
    if (k < P_) v =  2.0f * Cin[(n*P_ + k)*2 + 0];
    else        v = -2.0f * Cin[(n*P_ + (k-P_))*2 + 1];
    CMh[idx] = f2bf(v);
}

// ---------------- f32 -> bf16 conversion pass ----------------

__global__ __launch_bounds__(256) void conv_hi(const float* __restrict__ x,
                                               unsigned short* __restrict__ y) {
    size_t i = ((size_t)blockIdx.x * 256 + threadIdx.x) * 8;
    float4 a = *(const float4*)&x[i];
    float4 b = *(const float4*)&x[i + 4];
    u16x8 o;
    o[0] = f2bf(a.x); o[1] = f2bf(a.y); o[2] = f2bf(a.z); o[3] = f2bf(a.w);
    o[4] = f2bf(b.x); o[5] = f2bf(b.y); o[6] = f2bf(b.z); o[7] = f2bf(b.w);
    *(u16x8*)&y[i] = o;
}

// ---------------- MFMA GEMM: C = A(bf16) @ B^T (+ D*Din) ----------------
// A: [M][K] bf16. B: [N][K] bf16 (k-major rows).
// 128x128 tile, BK=64, 4 waves (2x2), 4x4 frags of 16x16x32.
// Pipelined K-loop (T3/T4): raw barrier, counted waits, stage-after-read:
//   { vmcnt(0) -> barrier -> ds_read(cur) -> lgkmcnt(0) -> stage(cur^1) -> MFMA }
// Prefetch stays in flight across the barrier; no full drain per step.
// LDS XOR-swizzled (slot ^= row&7) via pre-swizzled global source (rule #21).

template<int KSTEPS>
__global__ __launch_bounds__(256) void gemm_bf16(
        const unsigned short* __restrict__ A,
        const unsigned short* __restrict__ Bm,
        float* __restrict__ Cout, int N,
        const float* __restrict__ Din, const float* __restrict__ Dv) {
    constexpr int K = KSTEPS * 64;
    __shared__ unsigned short As[2][128 * 64];
    __shared__ unsigned short Bs[2][128 * 64];

    int t = threadIdx.x;
    // XCD-aware swizzle: contiguous chunk of flat ids per XCD (nwg % 8 == 0)
    int nx = gridDim.x;                       // 2 (gemm1) or 4 (gemm2), pow2
    int flat = blockIdx.x + nx * blockIdx.y;
    int per  = (nx * gridDim.y) >> 3;
    int nid  = (flat & 7) * per + (flat >> 3);
    int n0 = (nid & (nx - 1)) * 128;
    int m0 = (nid / nx) * 128;

    int lane = t & 63;
    int w    = t >> 6;
    int wr = w >> 1, wc = w & 1;
    int lr = lane & 15, lg = lane >> 4;

    // staging: thread t -> row t>>3 (0..31), slot t&7; source slot XOR-swizzled.
    int tr = t >> 3;
    int ss = (t & 7) ^ (tr & 7);
    const unsigned short* gA = A  + (size_t)(m0 + tr) * K + ss * 8;
    const unsigned short* gB = Bm + (size_t)(n0 + tr) * K + ss * 8;
    int ldst = w * 512;                        // wave-uniform base (elems)

    f32x4 acc[4][4] = {};

    // prologue: stage K-step 0 into buf 0 (8 loads in flight)
#pragma unroll
    for (int is = 0; is < 4; ++is) {
        gload16(gA + (size_t)is * 32 * K, &As[0][ldst + is * 2048]);
        gload16(gB + (size_t)is * 32 * K, &Bs[0][ldst + is * 2048]);
    }

    for (int ks = 0; ks < KSTEPS; ++ks) {
        int cur = ks & 1;
        // only the 8 loads for buf[cur] are in flight here
        asm volatile("s_waitcnt vmcnt(0)" ::: "memory");
        __builtin_amdgcn_sched_barrier(0);
        __builtin_amdgcn_s_barrier();          // all waves' quarter-tiles landed
        __builtin_amdgcn_sched_barrier(0);

        bf16x8 af[2][4], bf[2][4];
#pragma unroll
        for (int ku = 0; ku < 2; ++ku) {
            int slot = (((lg + ku * 4) ^ (lr & 7)) << 3);
#pragma unroll
            for (int f = 0; f < 4; ++f) {
                af[ku][f] = *(const bf16x8*)&As[cur][(wr * 64 + f * 16 + lr) * 64 + slot];
                bf[ku][f] = *(const bf16x8*)&Bs[cur][(wc * 64 + f * 16 + lr) * 64 + slot];
            }
        }
        // reads complete before this wave can reach the next barrier
        asm volatile("s_waitcnt lgkmcnt(0)" ::: "memory");
        __builtin_amdgcn_sched_barrier(0);

        if (ks + 1 < KSTEPS) {
            int k1 = (ks + 1) * 64;
#pragma unroll
            for (int is = 0; is < 4; ++is) {
                gload16(gA + (size_t)is * 32 * K + k1, &As[cur ^ 1][ldst + is * 2048]);
                gload16(gB + (size_t)is * 32 * K + k1, &Bs[cur ^ 1][ldst + is * 2048]);
            }
        }
        __builtin_amdgcn_sched_barrier(0);

        __builtin_amdgcn_s_setprio(1);
#pragma unroll
        for (int ku = 0; ku < 2; ++ku)
#pragma unroll
            for (int fm = 0; fm < 4; ++fm)
#pragma unroll
                for (int fn = 0; fn < 4; ++fn)
                    acc[fm][fn] = __builtin_amdgcn_mfma_f32_16x16x32_bf16(af[ku][fm], bf[ku][fn], acc[fm][fn], 0, 0, 0);
        __builtin_amdgcn_s_setprio(0);
    }

    // epilogue: C/D layout col=lane&15, row=(lane>>4)*4+reg
#pragma unroll
    for (int fm = 0; fm < 4; ++fm)
#pragma unroll
        for (int fn = 0; fn < 4; ++fn)
#pragma unroll
            for (int r = 0; r < 4; ++r) {
                int m = m0 + wr * 64 + fm * 16 + lg * 4 + r;
                int n = n0 + wc * 64 + fn * 16 + lr;
                float v = acc[fm][fn][r];
                if (Din) v += Dv[n] * Din[(size_t)m * N + n];
                Cout[(size_t)m * N + n] = v;
            }
}

// ---------------- decoupled scan over bu[b*l][256] ----------------

__global__ __launch_bounds__(256) void scan_carry(const float* __restrict__ bu,
        const float* __restrict__ ar_, const float* __restrict__ ai_,
        float* __restrict__ carr) {
    __shared__ float lds[64][256];
    int t = threadIdx.x;
    int c = blockIdx.x, b = blockIdx.y;
    size_t base = ((size_t)(b*L_ + c*256)) * N2_;
    float ar = 0.f, ai = 0.f, xr = 0.f, xi = 0.f;
    if (t < 128) { ar = ar_[t]; ai = ai_[t]; }
    for (int s = 0; s < 4; s++) {
        __syncthreads();
        const float* g = bu + base + (size_t)s * 64 * N2_;
#pragma unroll
        for (int it = 0; it < 16; it++) {
            int flat = it * 1024 + t * 4;
            *(float4*)&lds[0][flat] = *(const float4*)&g[flat];
        }
        __syncthreads();
        if (t < 128) {
            for (int i = 0; i < 64; i++) {
                float br = lds[i][t], bi = lds[i][t + 128];
                float nr = ar*xr - ai*xi + br;
                float ni = ar*xi + ai*xr + bi;
                xr = nr; xi = ni;
            }
        }
    }
    if (t < 128) {
        size_t o = ((size_t)(b*16 + c)) * N2_;
        carr[o + t] = xr; carr[o + t + 128] = xi;
    }
}

__global__ void scan_chunks(const float* __restrict__ carr, float* __restrict__ pre,
                            const float* __restrict__ ar_, const float* __restrict__ ai_) {
    int id = blockIdx.x * 256 + threadIdx.x;
    if (id >= B_ * P_) return;
    int b = id >> 7, p = id & (P_-1);
    float mr = ar_[p], mi = ai_[p];
#pragma unroll
    for (int s = 0; s < 8; s++) { float tr = mr*mr - mi*mi; mi = 2.f*mr*mi; mr = tr; }  // a^256
    float xr = 0.f, xi = 0.f;
    for (int c = 0; c < 16; c++) {
        size_t o = ((size_t)(b*16 + c)) * N2_;
        pre[o + p] = xr; pre[o + p + 128] = xi;
        float cr = carr[o + p], ci = carr[o + p + 128];
        float nr = mr*xr - mi*xi + cr;
        float ni = mr*xi + mi*xr + ci;
        xr = nr; xi = ni;
    }
}

// scan_apply: states emitted as bf16 [m][256] for gemm2's MFMA A-operand
__global__ __launch_bounds__(256) void scan_apply(const float* __restrict__ bu,
        const float* __restrict__ ar_, const float* __restrict__ ai_,
        const float* __restrict__ pre, unsigned short* __restrict__ states_h) {
    __shared__ float lds[64][256];
    int t = threadIdx.x;
    int c = blockIdx.x, b = blockIdx.y;
    size_t base = ((size_t)(b*L_ + c*256)) * N2_;
    float ar = 0.f, ai = 0.f, xr = 0.f, xi = 0.f;
    if (t < 128) {
        ar = ar_[t]; ai = ai_[t];
        size_t o = ((size_t)(b*16 + c)) * N2_;
        xr = pre[o + t]; xi = pre[o + t + 128];
    }
    for (int s = 0; s < 4; s++) {
        __syncthreads();
        const float* g = bu + base + (size_t)s * 64 * N2_;
#pragma unroll
        for (int it = 0; it < 16; it++) {
            int flat = it * 1024 + t * 4;
            *(float4*)&lds[0][flat] = *(const float4*)&g[flat];
        }
        __syncthreads();
        if (t < 128) {
            for (int i = 0; i < 64; i++) {
                float br = lds[i][t], bi = lds[i][t + 128];
                float nr = ar*xr - ai*xi + br;
                float ni = ar*xi + ai*xr + bi;
                xr = nr; xi = ni;
                lds[i][t] = xr; lds[i][t + 128] = xi;
            }
        }
        __syncthreads();
        unsigned short* o = states_h + base + (size_t)s * 64 * N2_;
#pragma unroll
        for (int it = 0; it < 8; it++) {
            int flat = it * 2048 + t * 8;
            float4 v0 = *(const float4*)&lds[0][flat];
            float4 v1 = *(const float4*)&lds[0][flat + 4];
            u16x8 ov;
            ov[0] = f2bf(v0.x); ov[1] = f2bf(v0.y); ov[2] = f2bf(v0.z); ov[3] = f2bf(v0.w);
            ov[4] = f2bf(v1.x); ov[5] = f2bf(v1.y); ov[6] = f2bf(v1.z); ov[7] = f2bf(v1.w);
            *(u16x8*)&o[flat] = ov;
        }
    }
}

// ---------------- launch ----------------

extern "C" void kernel_launch(void* const* d_in, const int* in_sizes, int n_in,
                              void* d_out, int out_size, void* d_ws, size_t ws_size,
                              hipStream_t stream) {
    const float* inputs = (const float*)d_in[0];
    const float* lr     = (const float*)d_in[1];
    const float* li     = (const float*)d_in[2];
    const float* Bin    = (const float*)d_in[3];
    const float* Cin    = (const float*)d_in[4];
    const float* Dv     = (const float*)d_in[5];
    const float* lstep  = (const float*)d_in[6];
    float* out = (float*)d_out;

    // d_out as scratch: bu f32 (64MB) | Ah bf16 (64MB).
    // gemm1 reads Ah (upper half), writes bu (lower half) - disjoint.
    // gemm2 reads NOTHING from d_out (Din = f32 inputs) and overwrites it all.
    char* ob = (char*)d_out;
    float*          bu = (float*)ob;
    unsigned short* Ah = (unsigned short*)(ob + 67108864);

    // d_ws (~34.6MB of proven 68MB)
    float* ws     = (float*)d_ws;
    float* abar_r = ws;
    float* abar_i = ws + 128;
    float* coef_r = ws + 256;
    float* coef_i = ws + 384;
    float* carr   = ws + 512;            // 65536 f32
    float* pre    = ws + 66048;          // 65536 f32
    unsigned short* BTh = (unsigned short*)(ws + 131584);   // 131072 u16
    unsigned short* CMh = BTh + N2_*H_;                     // 131072 u16
    unsigned short* states_h = CMh + H_*N2_;                // 16,777,216 u16

    hipLaunchKernelGGL(precompA, dim3(1), dim3(128), 0, stream,
                       lr, li, lstep, abar_r, abar_i, coef_r, coef_i);
    hipLaunchKernelGGL(precompBT, dim3((N2_*H_)/256), dim3(256), 0, stream,
                       Bin, coef_r, coef_i, BTh);
    hipLaunchKernelGGL(precompCM, dim3((H_*N2_)/256), dim3(256), 0, stream,
                       Cin, CMh);
    hipLaunchKernelGGL(conv_hi, dim3((M_*H_)/(256*8)), dim3(256), 0, stream,
                       inputs, Ah);
    // bu = Ah @ BT^T   (65536 x 512)*(512 x 256)
    hipLaunchKernelGGL((gemm_bf16<8>), dim3(N2_/128, M_/128), dim3(256), 0, stream,
                       Ah, BTh, bu, N2_, (const float*)nullptr, (const float*)nullptr);
    hipLaunchKernelGGL(scan_carry, dim3(16, B_), dim3(256), 0, stream,
                       bu, abar_r, abar_i, carr);
    hipLaunchKernelGGL(scan_chunks, dim3(8), dim3(256), 0, stream,
                       carr, pre, abar_r, abar_i);
    hipLaunchKernelGGL(scan_apply, dim3(16, B_), dim3(256), 0, stream,
                       bu, abar_r, abar_i, pre, states_h);
    // out = states @ CM^T + D*inputs   (65536 x 256)*(256 x 512)
    hipLaunchKernelGGL((gemm_bf16<4>), dim3(H_/128, M_/128), dim3(256), 0, stream,
                       states_h, CMh, out, H_, inputs, Dv);
}

// Round 8
// 197.655 us; speedup vs baseline: 2.5493x; 1.2772x over previous
//
#include <hip/hip_runtime.h>
#include <math.h>

#define B_   16
#define L_   4096
#define H_   512
#define P_   128
#define M_   (B_*L_)    // 65536
#define N2_  (2*P_)     // 256

typedef __attribute__((ext_vector_type(8))) short bf16x8;
typedef __attribute__((ext_vector_type(8))) unsigned short u16x8;
typedef __attribute__((ext_vector_type(4))) float f32x4;

__device__ __forceinline__ unsigned short f2bf(float x) {
    unsigned u = __float_as_uint(x);
    return (unsigned short)((u + 0x7FFFu + ((u >> 16) & 1u)) >> 16);
}
__device__ __forceinline__ float bf2f(unsigned short s) {
    return __uint_as_float(((unsigned)s) << 16);
}

__device__ __forceinline__ void gload16(const void* g, void* l) {
    __builtin_amdgcn_global_load_lds(
        (const __attribute__((address_space(1))) void*)g,
        (__attribute__((address_space(3))) void*)l,
        16, 0, 0);
}

// ---------------- precompute ----------------

__global__ void precompA(const float* __restrict__ lr, const float* __restrict__ li,
                         const float* __restrict__ lstep,
                         float* __restrict__ abar_r, float* __restrict__ abar_i,
                         float* __restrict__ coef_r, float* __restrict__ coef_i) {
    int p = threadIdx.x;
    if (p >= P_) return;
    double lrd = (double)lr[p], lid = (double)li[p];
    double step = exp((double)lstep[p]);       // STEP_RESCALE = 1
    double ea = exp(lrd * step);
    double abr = ea * cos(lid * step), abi = ea * sin(lid * step);
    abar_r[p] = (float)abr; abar_i[p] = (float)abi;
    double nr = abr - 1.0, ni = abi;
    double den = lrd*lrd + lid*lid;
    coef_r[p] = (float)((nr*lrd + ni*lid) / den);
    coef_i[p] = (float)((ni*lrd - nr*lid) / den);
}

// BT[n][k=h]: n<128 -> Re(coef_p * B_c[p][h]), n>=128 -> Im. bf16.
__global__ void precompBT(const float* __restrict__ Bin,
                          const float* __restrict__ coef_r, const float* __restrict__ coef_i,
                          unsigned short* __restrict__ BTh) {
    int idx = blockIdx.x * 256 + threadIdx.x;   // over 256*512
    if (idx >= N2_*H_) return;
    int n = idx >> 9, k = idx & 511;
    int p = n & (P_-1);
    float br = Bin[(p*H_ + k)*2 + 0], bi = Bin[(p*H_ + k)*2 + 1];
    float cr = coef_r[p], ci = coef_i[p];
    float v = (n < P_) ? (cr*br - ci*bi) : (cr*bi + ci*br);
    BTh[idx] = f2bf(v);
}

// CM[n=h][k]: k<128 -> 2*C_r[h][k], k>=128 -> -2*C_i[h][k-128]. bf16.
__global__ void precompCM(const float* __restrict__ Cin,
                          unsigned short* __restrict__ CMh) {
    int idx = blockIdx.x * 256 + threadIdx.x;   // over 512*256
    if (idx >= H_*N2_) return;
    int n = idx >> 8, k = idx & 255;
    float v;
    if (k < P_) v =  2.0f * Cin[(n*P_ + k)*2 + 0];
    else        v = -2.0f * Cin[(n*P_ + (k-P_))*2 + 1];
    CMh[idx] = f2bf(v);
}

// ---------------- f32 -> bf16 conversion pass ----------------

__global__ __launch_bounds__(256) void conv_hi(const float* __restrict__ x,
                                               unsigned short* __restrict__ y) {
    size_t i = ((size_t)blockIdx.x * 256 + threadIdx.x) * 8;
    float4 a = *(const float4*)&x[i];
    float4 b = *(const float4*)&x[i + 4];
    u16x8 o;
    o[0] = f2bf(a.x); o[1] = f2bf(a.y); o[2] = f2bf(a.z); o[3] = f2bf(a.w);
    o[4] = f2bf(b.x); o[5] = f2bf(b.y); o[6] = f2bf(b.z); o[7] = f2bf(b.w);
    *(u16x8*)&y[i] = o;
}

// ---------------- MFMA GEMM, m97 structure ----------------
// A: [M][K] bf16. B: [N][K] bf16. C: [M][N] f32 (+ optional D*Din).
// 128x128 tile, BK=32, SINGLE-buffered 16KB LDS -> 3+ blocks/CU,
// plain 2-barrier K-loop (implicit wave-level overlap does the pipelining).
// Swapped-operand MFMA: acc[fn][fm] = mfma(bf, af, .) so each lane holds
// 4 consecutive-n outputs -> float4 C stores / float4 D*Din loads.

template<int KSTEPS, bool HASD>
__global__ __launch_bounds__(256) void gemm_m97(
        const unsigned short* __restrict__ A,
        const unsigned short* __restrict__ Bm,
        float* __restrict__ Cout, int N,
        const float* __restrict__ Din, const float* __restrict__ Dv) {
    constexpr int K = KSTEPS * 32;
    __shared__ unsigned short As[128 * 32];
    __shared__ unsigned short Bs[128 * 32];

    int t = threadIdx.x;
    // XCD-aware swizzle (nwg % 8 == 0)
    int nx = gridDim.x;
    int flat = blockIdx.x + nx * blockIdx.y;
    int per  = (nx * gridDim.y) >> 3;
    int nid  = (flat & 7) * per + (flat >> 3);
    int n0 = (nid & (nx - 1)) * 128;
    int m0 = (nid / nx) * 128;

    int lane = t & 63;
    int w    = t >> 6;
    int wr = w >> 1, wc = w & 1;
    int lr = lane & 15, lg = lane >> 4;

    // staging: per issue 64 rows x 32 shorts (4KB); thread t -> row t>>2, 16B quarter t&3.
    // LDS offset = t*8 shorts (linear); wave-uniform base = w*512.
    int srow = t >> 2;
    int sq   = t & 3;
    const unsigned short* gA = A  + (size_t)(m0 + srow) * K + sq * 8;
    const unsigned short* gB = Bm + (size_t)(n0 + srow) * K + sq * 8;
    int ldsb = w * 512;

    f32x4 acc[4][4] = {};      // acc[fn][fm], transposed accumulation

    for (int ks = 0; ks < KSTEPS; ++ks) {
        int k0 = ks * 32;
        __syncthreads();
        gload16(gA + k0,                      As + ldsb);
        gload16(gA + (size_t)64 * K + k0,     As + 2048 + ldsb);
        gload16(gB + k0,                      Bs + ldsb);
        gload16(gB + (size_t)64 * K + k0,     Bs + 2048 + ldsb);
        __syncthreads();

        bf16x8 af[4], bf[4];
#pragma unroll
        for (int f = 0; f < 4; ++f) {
            af[f] = *(const bf16x8*)&As[(wr * 64 + f * 16 + lr) * 32 + lg * 8];
            bf[f] = *(const bf16x8*)&Bs[(wc * 64 + f * 16 + lr) * 32 + lg * 8];
        }
#pragma unroll
        for (int fn = 0; fn < 4; ++fn)
#pragma unroll
            for (int fm = 0; fm < 4; ++fm)
                acc[fn][fm] = __builtin_amdgcn_mfma_f32_16x16x32_bf16(bf[fn], af[fm], acc[fn][fm], 0, 0, 0);
    }

    // epilogue: swapped D layout -> lane lr = m (col), regs = 4 consecutive n (rows lg*4+r)
#pragma unroll
    for (int fn = 0; fn < 4; ++fn)
#pragma unroll
        for (int fm = 0; fm < 4; ++fm) {
            int m = m0 + wr * 64 + fm * 16 + lr;
            int n = n0 + wc * 64 + fn * 16 + lg * 4;
            float4 v = make_float4(acc[fn][fm][0], acc[fn][fm][1], acc[fn][fm][2], acc[fn][fm][3]);
            if (HASD) {
                float4 di = *(const float4*)&Din[(size_t)m * N + n];
                float4 dv = *(const float4*)&Dv[n];
                v.x += dv.x * di.x; v.y += dv.y * di.y;
                v.z += dv.z * di.z; v.w += dv.w * di.w;
            }
            *(float4*)&Cout[(size_t)m * N + n] = v;
        }
}

// ---------------- decoupled scan over bu[b*l][256] ----------------

__global__ __launch_bounds__(256) void scan_carry(const float* __restrict__ bu,
        const float* __restrict__ ar_, const float* __restrict__ ai_,
        float* __restrict__ carr) {
    __shared__ float lds[64][256];
    int t = threadIdx.x;
    int c = blockIdx.x, b = blockIdx.y;
    size_t base = ((size_t)(b*L_ + c*256)) * N2_;
    float ar = 0.f, ai = 0.f, xr = 0.f, xi = 0.f;
    if (t < 128) { ar = ar_[t]; ai = ai_[t]; }
    for (int s = 0; s < 4; s++) {
        __syncthreads();
        const float* g = bu + base + (size_t)s * 64 * N2_;
#pragma unroll
        for (int it = 0; it < 16; it++) {
            int flat = it * 1024 + t * 4;
            *(float4*)&lds[0][flat] = *(const float4*)&g[flat];
        }
        __syncthreads();
        if (t < 128) {
            for (int i = 0; i < 64; i++) {
                float br = lds[i][t], bi = lds[i][t + 128];
                float nr = ar*xr - ai*xi + br;
                float ni = ar*xi + ai*xr + bi;
                xr = nr; xi = ni;
            }
        }
    }
    if (t < 128) {
        size_t o = ((size_t)(b*16 + c)) * N2_;
        carr[o + t] = xr; carr[o + t + 128] = xi;
    }
}

__global__ void scan_chunks(const float* __restrict__ carr, float* __restrict__ pre,
                            const float* __restrict__ ar_, const float* __restrict__ ai_) {
    int id = blockIdx.x * 256 + threadIdx.x;
    if (id >= B_ * P_) return;
    int b = id >> 7, p = id & (P_-1);
    float mr = ar_[p], mi = ai_[p];
#pragma unroll
    for (int s = 0; s < 8; s++) { float tr = mr*mr - mi*mi; mi = 2.f*mr*mi; mr = tr; }  // a^256
    float xr = 0.f, xi = 0.f;
    for (int c = 0; c < 16; c++) {
        size_t o = ((size_t)(b*16 + c)) * N2_;
        pre[o + p] = xr; pre[o + p + 128] = xi;
        float cr = carr[o + p], ci = carr[o + p + 128];
        float nr = mr*xr - mi*xi + cr;
        float ni = mr*xi + mi*xr + ci;
        xr = nr; xi = ni;
    }
}

// scan_apply: states emitted as bf16 [m][256] for gemm2's MFMA A-operand
__global__ __launch_bounds__(256) void scan_apply(const float* __restrict__ bu,
        const float* __restrict__ ar_, const float* __restrict__ ai_,
        const float* __restrict__ pre, unsigned short* __restrict__ states_h) {
    __shared__ float lds[64][256];
    int t = threadIdx.x;
    int c = blockIdx.x, b = blockIdx.y;
    size_t base = ((size_t)(b*L_ + c*256)) * N2_;
    float ar = 0.f, ai = 0.f, xr = 0.f, xi = 0.f;
    if (t < 128) {
        ar = ar_[t]; ai = ai_[t];
        size_t o = ((size_t)(b*16 + c)) * N2_;
        xr = pre[o + t]; xi = pre[o + t + 128];
    }
    for (int s = 0; s < 4; s++) {
        __syncthreads();
        const float* g = bu + base + (size_t)s * 64 * N2_;
#pragma unroll
        for (int it = 0; it < 16; it++) {
            int flat = it * 1024 + t * 4;
            *(float4*)&lds[0][flat] = *(const float4*)&g[flat];
        }
        __syncthreads();
        if (t < 128) {
            for (int i = 0; i < 64; i++) {
                float br = lds[i][t], bi = lds[i][t + 128];
                float nr = ar*xr - ai*xi + br;
                float ni = ar*xi + ai*xr + bi;
                xr = nr; xi = ni;
                lds[i][t] = xr; lds[i][t + 128] = xi;
            }
        }
        __syncthreads();
        unsigned short* o = states_h + base + (size_t)s * 64 * N2_;
#pragma unroll
        for (int it = 0; it < 8; it++) {
            int flat = it * 2048 + t * 8;
            float4 v0 = *(const float4*)&lds[0][flat];
            float4 v1 = *(const float4*)&lds[0][flat + 4];
            u16x8 ov;
            ov[0] = f2bf(v0.x); ov[1] = f2bf(v0.y); ov[2] = f2bf(v0.z); ov[3] = f2bf(v0.w);
            ov[4] = f2bf(v1.x); ov[5] = f2bf(v1.y); ov[6] = f2bf(v1.z); ov[7] = f2bf(v1.w);
            *(u16x8*)&o[flat] = ov;
        }
    }
}

// ---------------- launch ----------------

extern "C" void kernel_launch(void* const* d_in, const int* in_sizes, int n_in,
                              void* d_out, int out_size, void* d_ws, size_t ws_size,
                              hipStream_t stream) {
    const float* inputs = (const float*)d_in[0];
    const float* lr     = (const float*)d_in[1];
    const float* li     = (const float*)d_in[2];
    const float* Bin    = (const float*)d_in[3];
    const float* Cin    = (const float*)d_in[4];
    const float* Dv     = (const float*)d_in[5];
    const float* lstep  = (const float*)d_in[6];
    float* out = (float*)d_out;

    // d_out as scratch: bu f32 (64MB) | Ah bf16 (64MB).
    // gemm1 reads Ah (upper half), writes bu (lower half) - disjoint.
    // gemm2 reads nothing from d_out (Din = f32 inputs) and overwrites it all.
    char* ob = (char*)d_out;
    float*          bu = (float*)ob;
    unsigned short* Ah = (unsigned short*)(ob + 67108864);

    // d_ws (~34.6MB of proven 68MB)
    float* ws     = (float*)d_ws;
    float* abar_r = ws;
    float* abar_i = ws + 128;
    float* coef_r = ws + 256;
    float* coef_i = ws + 384;
    float* carr   = ws + 512;            // 65536 f32
    float* pre    = ws + 66048;          // 65536 f32
    unsigned short* BTh = (unsigned short*)(ws + 131584);   // 131072 u16
    unsigned short* CMh = BTh + N2_*H_;                     // 131072 u16
    unsigned short* states_h = CMh + H_*N2_;                // 16,777,216 u16

    hipLaunchKernelGGL(precompA, dim3(1), dim3(128), 0, stream,
                       lr, li, lstep, abar_r, abar_i, coef_r, coef_i);
    hipLaunchKernelGGL(precompBT, dim3((N2_*H_)/256), dim3(256), 0, stream,
                       Bin, coef_r, coef_i, BTh);
    hipLaunchKernelGGL(precompCM, dim3((H_*N2_)/256), dim3(256), 0, stream,
                       Cin, CMh);
    hipLaunchKernelGGL(conv_hi, dim3((M_*H_)/(256*8)), dim3(256), 0, stream,
                       inputs, Ah);
    // bu = Ah @ BT^T   (65536 x 512)*(512 x 256)
    hipLaunchKernelGGL((gemm_m97<16, false>), dim3(N2_/128, M_/128), dim3(256), 0, stream,
                       Ah, BTh, bu, N2_, (const float*)nullptr, (const float*)nullptr);
    hipLaunchKernelGGL(scan_carry, dim3(16, B_), dim3(256), 0, stream,
                       bu, abar_r, abar_i, carr);
    hipLaunchKernelGGL(scan_chunks, dim3(8), dim3(256), 0, stream,
                       carr, pre, abar_r, abar_i);
    hipLaunchKernelGGL(scan_apply, dim3(16, B_), dim3(256), 0, stream,
                       bu, abar_r, abar_i, pre, states_h);
    // out = states @ CM^T + D*inputs   (65536 x 256)*(256 x 512)
    hipLaunchKernelGGL((gemm_m97<8, true>), dim3(H_/128, M_/128), dim3(256), 0, stream,
                       states_h, CMh, out, H_, inputs, Dv);
}